// Round 1
// baseline (190.179 us; speedup 1.0000x reference)
//
#include <hip/hip_runtime.h>
#include <hip/hip_bf16.h>
#include <math.h>

// Decoder: out[e] = sigmoid(relu( W2 . relu( W1 * [x[src_e]; x[dst_e]] + b1 ) + b2 ))
// GEMM1 via bf16 MFMA (fp32 accumulate), everything else fused in epilogue.

typedef short s16x4 __attribute__((ext_vector_type(4)));
typedef short s16x8 __attribute__((ext_vector_type(8)));
typedef float f32x4 __attribute__((ext_vector_type(4)));

#define D    128
#define BM   128      // edges per block
#define BK   64       // K-tile
#define LDT  72       // BK + 8 pad (breaks 128B-stride bank alias)
#define NKI  4        // 256 / BK

static __device__ inline short f2bf(float f) {
    // round-to-nearest-even fp32 -> bf16 bits
    unsigned u = __builtin_bit_cast(unsigned, f);
    unsigned r = (u + 0x7FFFu + ((u >> 16) & 1u)) >> 16;
    return (short)r;
}

__global__ __launch_bounds__(256) void decoder_kernel(
    const float* __restrict__ x,    // [N,128]
    const int*   __restrict__ ei,   // [2,E]
    const float* __restrict__ W1,   // [128,256] row-major = B^T layout
    const float* __restrict__ b1,   // [128]
    const float* __restrict__ W2,   // [128]
    const float* __restrict__ b2,   // [1]
    float*       __restrict__ out,  // [E]
    int E)
{
    __shared__ int   nid[2][BM];
    __shared__ short At[BM * LDT];
    __shared__ short Bt[D * LDT];
    __shared__ float rowsum[BM][2];

    const int tid = threadIdx.x;
    const int e0  = blockIdx.x * BM;

    // stage node ids (src for rows via k<128, dst for k>=128)
    if (tid < BM) {
        int e = e0 + tid;
        nid[0][tid] = (e < E) ? ei[e] : 0;
    } else {
        int e = e0 + (tid - BM);
        nid[1][tid - BM] = (e < E) ? ei[E + e] : 0;
    }

    const int wid  = tid >> 6;
    const int lane = tid & 63;
    const int wm = wid >> 1, wn = wid & 1;   // 2x2 wave tiling of 128x128
    const int quad = lane >> 4, l15 = lane & 15;

    const int srow = tid >> 4;        // 0..15 : staging row within pass
    const int scol = (tid & 15) * 4;  // 0..60 : staging float4 offset

    f32x4 acc[4][4] = {};

    __syncthreads();

    for (int t = 0; t < NKI; ++t) {
        const int* ids = nid[t >> 1];      // t=0,1 -> src ; t=2,3 -> dst
        const int kx = (t & 1) * BK;       // offset into x row
        const int kw = t * BK;             // offset into W1 row (global k)

        // stage A: 128 gathered rows x 64 k (fp32 -> bf16)
        #pragma unroll
        for (int p = 0; p < 8; ++p) {
            int row  = srow + p * 16;
            int node = ids[row];
            float4 v = *(const float4*)&x[(size_t)node * D + kx + scol];
            s16x4 bv = { f2bf(v.x), f2bf(v.y), f2bf(v.z), f2bf(v.w) };
            *(s16x4*)&At[row * LDT + scol] = bv;
        }
        // stage B = W1 rows (n-major, k contiguous -> B^T layout, frag-read friendly)
        #pragma unroll
        for (int p = 0; p < 8; ++p) {
            int n = srow + p * 16;
            float4 v = *(const float4*)&W1[n * 256 + kw + scol];
            s16x4 bv = { f2bf(v.x), f2bf(v.y), f2bf(v.z), f2bf(v.w) };
            *(s16x4*)&Bt[n * LDT + scol] = bv;
        }
        __syncthreads();

        #pragma unroll
        for (int c = 0; c < 2; ++c) {       // two K=32 chunks per BK=64
            const int kc = c * 32;
            s16x8 af[4], bfr[4];
            #pragma unroll
            for (int i = 0; i < 4; ++i)
                af[i] = *(const s16x8*)&At[(wm*64 + i*16 + l15) * LDT + kc + quad*8];
            #pragma unroll
            for (int j = 0; j < 4; ++j)
                bfr[j] = *(const s16x8*)&Bt[(wn*64 + j*16 + l15) * LDT + kc + quad*8];
            #pragma unroll
            for (int i = 0; i < 4; ++i)
                #pragma unroll
                for (int j = 0; j < 4; ++j)
                    acc[i][j] = __builtin_amdgcn_mfma_f32_16x16x32_bf16(
                        af[i], bfr[j], acc[i][j], 0, 0, 0);
        }
        __syncthreads();
    }

    // epilogue: per edge-row: sum_n relu(C + b1[n]) * W2[n], then +b2, relu, sigmoid
    // C/D layout (m89/m91): col = lane&15, row = quad*4 + reg
    float b1v[4], w2v[4];
    #pragma unroll
    for (int j = 0; j < 4; ++j) {
        int col = wn*64 + j*16 + l15;
        b1v[j] = b1[col];
        w2v[j] = W2[col];
    }
    float psum[16];
    #pragma unroll
    for (int t = 0; t < 16; ++t) psum[t] = 0.f;
    #pragma unroll
    for (int i = 0; i < 4; ++i)
        #pragma unroll
        for (int j = 0; j < 4; ++j)
            #pragma unroll
            for (int r = 0; r < 4; ++r) {
                float c = acc[i][j][r] + b1v[j];
                c = fmaxf(c, 0.f);
                psum[i*4 + r] += c * w2v[j];
            }
    // reduce over the 16 column-lanes (bits 0..3 of lane id)
    #pragma unroll
    for (int off = 1; off < 16; off <<= 1)
        #pragma unroll
        for (int t = 0; t < 16; ++t)
            psum[t] += __shfl_xor(psum[t], off);

    if (l15 == 0) {
        #pragma unroll
        for (int i = 0; i < 4; ++i)
            #pragma unroll
            for (int r = 0; r < 4; ++r)
                rowsum[wm*64 + i*16 + quad*4 + r][wn] = psum[i*4 + r];
    }
    __syncthreads();

    if (tid < BM) {
        int e = e0 + tid;
        if (e < E) {
            float s = rowsum[tid][0] + rowsum[tid][1] + b2[0];
            s = fmaxf(s, 0.f);
            out[e] = 1.0f / (1.0f + expf(-s));
        }
    }
}

extern "C" void kernel_launch(void* const* d_in, const int* in_sizes, int n_in,
                              void* d_out, int out_size, void* d_ws, size_t ws_size,
                              hipStream_t stream) {
    const float* x  = (const float*)d_in[0];
    const int*   ei = (const int*)d_in[1];
    const float* W1 = (const float*)d_in[2];
    const float* b1 = (const float*)d_in[3];
    const float* W2 = (const float*)d_in[4];
    const float* b2 = (const float*)d_in[5];
    float* out = (float*)d_out;

    int E = in_sizes[1] / 2;
    int nblocks = (E + BM - 1) / BM;
    decoder_kernel<<<nblocks, 256, 0, stream>>>(x, ei, W1, b1, W2, b2, out, E);
}

// Round 2
// 170.279 us; speedup vs baseline: 1.1169x; 1.1169x over previous
//
#include <hip/hip_runtime.h>
#include <hip/hip_bf16.h>
#include <math.h>

// Decoder: out[e] = sigmoid(relu( W2 . relu( W1 * [x[src_e]; x[dst_e]] + b1 ) + b2 ))
// GEMM1 via bf16 MFMA (fp32 accumulate), fused epilogue.
// R2: pre-convert x and W1 to bf16 in d_ws -> halves the random-gather traffic
//     (dominant cost per R1 rocprof: FETCH_SIZE 293 MB, gather-bound).

typedef short s16x4 __attribute__((ext_vector_type(4)));
typedef short s16x8 __attribute__((ext_vector_type(8)));
typedef float f32x4 __attribute__((ext_vector_type(4)));

#define D    128
#define BM   128      // edges per block
#define BK   64       // K-tile
#define LDT  72       // BK + 8 pad (breaks 128B-stride bank alias)
#define NKI  4        // 256 / BK

static __device__ inline short f2bf(float f) {
    // round-to-nearest-even fp32 -> bf16 bits
    unsigned u = __builtin_bit_cast(unsigned, f);
    unsigned r = (u + 0x7FFFu + ((u >> 16) & 1u)) >> 16;
    return (short)r;
}

__global__ __launch_bounds__(256) void convert_bf16_kernel(
    const float* __restrict__ src, short* __restrict__ dst, int n4)
{
    int i = blockIdx.x * blockDim.x + threadIdx.x;
    if (i < n4) {
        float4 v = ((const float4*)src)[i];
        s16x4 b = { f2bf(v.x), f2bf(v.y), f2bf(v.z), f2bf(v.w) };
        ((s16x4*)dst)[i] = b;
    }
}

// BF16IN=true: xin/w1in are pre-converted bf16 (short). false: raw fp32.
template <bool BF16IN>
__global__ __launch_bounds__(256) void decoder_kernel(
    const void*  __restrict__ xin,   // [N,128]
    const int*   __restrict__ ei,    // [2,E]
    const void*  __restrict__ w1in,  // [128,256] row-major = B^T layout
    const float* __restrict__ b1,    // [128]
    const float* __restrict__ W2,    // [128]
    const float* __restrict__ b2,    // [1]
    float*       __restrict__ out,   // [E]
    int E)
{
    __shared__ int   nid[2][BM];
    __shared__ short At[BM * LDT];
    __shared__ short Bt[D * LDT];
    __shared__ float rowsum[BM][2];

    const int tid = threadIdx.x;
    const int e0  = blockIdx.x * BM;

    if (tid < BM) {
        int e = e0 + tid;
        nid[0][tid] = (e < E) ? ei[e] : 0;
    } else {
        int e = e0 + (tid - BM);
        nid[1][tid - BM] = (e < E) ? ei[E + e] : 0;
    }

    const int wid  = tid >> 6;
    const int lane = tid & 63;
    const int wm = wid >> 1, wn = wid & 1;   // 2x2 wave tiling of 128x128
    const int quad = lane >> 4, l15 = lane & 15;

    const int srow = tid >> 4;        // 0..15 : staging row within pass
    const int scol = (tid & 15) * 4;  // element offset (x4 per thread)

    f32x4 acc[4][4] = {};

    __syncthreads();

    for (int t = 0; t < NKI; ++t) {
        const int* ids = nid[t >> 1];      // t=0,1 -> src ; t=2,3 -> dst
        const int kx = (t & 1) * BK;       // offset into x row
        const int kw = t * BK;             // offset into W1 row (global k)

        // stage A: 128 gathered rows x 64 k
        #pragma unroll
        for (int p = 0; p < 8; ++p) {
            int row  = srow + p * 16;
            int node = ids[row];
            if (BF16IN) {
                const short* xb = (const short*)xin;
                s16x4 v = *(const s16x4*)&xb[(size_t)node * D + kx + scol];
                *(s16x4*)&At[row * LDT + scol] = v;
            } else {
                const float* xf = (const float*)xin;
                float4 v = *(const float4*)&xf[(size_t)node * D + kx + scol];
                s16x4 bv = { f2bf(v.x), f2bf(v.y), f2bf(v.z), f2bf(v.w) };
                *(s16x4*)&At[row * LDT + scol] = bv;
            }
        }
        // stage B = W1 rows (n-major, k contiguous -> B^T layout)
        #pragma unroll
        for (int p = 0; p < 8; ++p) {
            int n = srow + p * 16;
            if (BF16IN) {
                const short* wb = (const short*)w1in;
                s16x4 v = *(const s16x4*)&wb[n * 256 + kw + scol];
                *(s16x4*)&Bt[n * LDT + scol] = v;
            } else {
                const float* wf = (const float*)w1in;
                float4 v = *(const float4*)&wf[n * 256 + kw + scol];
                s16x4 bv = { f2bf(v.x), f2bf(v.y), f2bf(v.z), f2bf(v.w) };
                *(s16x4*)&Bt[n * LDT + scol] = bv;
            }
        }
        __syncthreads();

        #pragma unroll
        for (int c = 0; c < 2; ++c) {       // two K=32 chunks per BK=64
            const int kc = c * 32;
            s16x8 af[4], bfr[4];
            #pragma unroll
            for (int i = 0; i < 4; ++i)
                af[i] = *(const s16x8*)&At[(wm*64 + i*16 + l15) * LDT + kc + quad*8];
            #pragma unroll
            for (int j = 0; j < 4; ++j)
                bfr[j] = *(const s16x8*)&Bt[(wn*64 + j*16 + l15) * LDT + kc + quad*8];
            #pragma unroll
            for (int i = 0; i < 4; ++i)
                #pragma unroll
                for (int j = 0; j < 4; ++j)
                    acc[i][j] = __builtin_amdgcn_mfma_f32_16x16x32_bf16(
                        af[i], bfr[j], acc[i][j], 0, 0, 0);
        }
        __syncthreads();
    }

    // epilogue: per edge-row: sum_n relu(C + b1[n]) * W2[n], then +b2, relu, sigmoid
    // C/D layout (m89/m91): col = lane&15, row = quad*4 + reg
    float b1v[4], w2v[4];
    #pragma unroll
    for (int j = 0; j < 4; ++j) {
        int col = wn*64 + j*16 + l15;
        b1v[j] = b1[col];
        w2v[j] = W2[col];
    }
    float psum[16];
    #pragma unroll
    for (int t = 0; t < 16; ++t) psum[t] = 0.f;
    #pragma unroll
    for (int i = 0; i < 4; ++i)
        #pragma unroll
        for (int j = 0; j < 4; ++j)
            #pragma unroll
            for (int r = 0; r < 4; ++r) {
                float c = acc[i][j][r] + b1v[j];
                c = fmaxf(c, 0.f);
                psum[i*4 + r] += c * w2v[j];
            }
    // reduce over the 16 column-lanes (bits 0..3 of lane id)
    #pragma unroll
    for (int off = 1; off < 16; off <<= 1)
        #pragma unroll
        for (int t = 0; t < 16; ++t)
            psum[t] += __shfl_xor(psum[t], off);

    if (l15 == 0) {
        #pragma unroll
        for (int i = 0; i < 4; ++i)
            #pragma unroll
            for (int r = 0; r < 4; ++r)
                rowsum[wm*64 + i*16 + quad*4 + r][wn] = psum[i*4 + r];
    }
    __syncthreads();

    if (tid < BM) {
        int e = e0 + tid;
        if (e < E) {
            float s = rowsum[tid][0] + rowsum[tid][1] + b2[0];
            s = fmaxf(s, 0.f);
            out[e] = 1.0f / (1.0f + expf(-s));
        }
    }
}

extern "C" void kernel_launch(void* const* d_in, const int* in_sizes, int n_in,
                              void* d_out, int out_size, void* d_ws, size_t ws_size,
                              hipStream_t stream) {
    const float* x  = (const float*)d_in[0];
    const int*   ei = (const int*)d_in[1];
    const float* W1 = (const float*)d_in[2];
    const float* b1 = (const float*)d_in[3];
    const float* W2 = (const float*)d_in[4];
    const float* b2 = (const float*)d_in[5];
    float* out = (float*)d_out;

    int E = in_sizes[1] / 2;
    int nblocks = (E + BM - 1) / BM;

    size_t x_elems  = (size_t)in_sizes[0];   // 12.8M
    size_t w1_elems = (size_t)in_sizes[2];   // 32768
    size_t need = (x_elems + w1_elems) * sizeof(short);

    if (ws_size >= need) {
        short* xb  = (short*)d_ws;
        short* w1b = xb + x_elems;
        int n4x = (int)(x_elems / 4);
        int n4w = (int)(w1_elems / 4);
        convert_bf16_kernel<<<(n4x + 255) / 256, 256, 0, stream>>>(x, xb, n4x);
        convert_bf16_kernel<<<(n4w + 255) / 256, 256, 0, stream>>>(W1, w1b, n4w);
        decoder_kernel<true><<<nblocks, 256, 0, stream>>>(
            xb, ei, w1b, b1, W2, b2, out, E);
    } else {
        decoder_kernel<false><<<nblocks, 256, 0, stream>>>(
            x, ei, W1, b1, W2, b2, out, E);
    }
}